// Round 2
// baseline (418.253 us; speedup 1.0000x reference)
//
#include <hip/hip_runtime.h>
#include <stdint.h>

typedef unsigned short ushort_t;
typedef unsigned int uint32;

typedef __attribute__((ext_vector_type(8))) short short8;
typedef __attribute__((ext_vector_type(4))) float floatx4;

#define NEG_SLOPE 0.2f

__device__ __forceinline__ ushort_t f2bf(float f) {
    union { float f; uint32 u; } v; v.f = f;
    uint32 u = v.u;
    uint32 r = (u + 0x7fffu + ((u >> 16) & 1u)) >> 16;
    return (ushort_t)r;
}
__device__ __forceinline__ float2 bf2x(uint32 u) {
    union { uint32 u; float f; } a, b;
    a.u = u << 16; b.u = u & 0xffff0000u;
    float2 r; r.x = a.f; r.y = b.f; return r;
}

// ---------------- dtype sniffer ----------------
// For bf16-pair data the low halfword is a bf16 of ~N(0,1): exp field in [100,140]
// essentially always. For f32 data low 16 bits are uniform mantissa: ~16% in range.
__global__ void k_sniff(const uint32* __restrict__ x, int* __restrict__ flag) {
    __shared__ int sh[256];
    int t = threadIdx.x;
    int c = 0;
    for (int i = t; i < 1024; i += 256) {
        uint32 h = x[i] & 0xFFFFu;
        uint32 e = (h >> 7) & 0xFFu;
        if (h == 0u || (e >= 100u && e <= 140u)) c++;
    }
    sh[t] = c; __syncthreads();
    for (int off = 128; off >= 1; off >>= 1) {
        if (t < off) sh[t] += sh[t + off];
        __syncthreads();
    }
    if (t == 0) flag[0] = (sh[0] >= 512) ? 1 : 0;
}

// canonicalize a float-typed input to bf16 (copy if already bf16)
__global__ void k_canon(const void* __restrict__ src, ushort_t* __restrict__ dst,
                        int n, const int* __restrict__ flag) {
    int i = blockIdx.x * 256 + threadIdx.x;
    if (i >= n) return;
    if (flag[0]) dst[i] = ((const ushort_t*)src)[i];
    else         dst[i] = f2bf(((const float*)src)[i]);
}

// canonicalize all 12 parameter tensors into one contiguous bf16 block:
// [0,49152): W0,W1,W2 (16384 ea)  [49152,49536): asrc0..2 (128 ea)
// [49536,49920): adst0..2         [49920,50304): b0..2
__global__ void k_canon_params(const void* W0, const void* W1, const void* W2,
                               const void* s0, const void* s1, const void* s2,
                               const void* a0, const void* a1, const void* a2,
                               const void* b0, const void* b1, const void* b2,
                               ushort_t* __restrict__ dst, const int* __restrict__ flag) {
    int i = blockIdx.x * 256 + threadIdx.x;
    if (i >= 50304) return;
    const void* src; int off;
    if (i < 49152) {
        int seg = i / 16384; off = i % 16384;
        src = seg == 0 ? W0 : seg == 1 ? W1 : W2;
    } else if (i < 49536) {
        int j = i - 49152; int seg = j / 128; off = j % 128;
        src = seg == 0 ? s0 : seg == 1 ? s1 : s2;
    } else if (i < 49920) {
        int j = i - 49536; int seg = j / 128; off = j % 128;
        src = seg == 0 ? a0 : seg == 1 ? a1 : a2;
    } else {
        int j = i - 49920; int seg = j / 128; off = j % 128;
        src = seg == 0 ? b0 : seg == 1 ? b1 : b2;
    }
    if (flag[0]) dst[i] = ((const ushort_t*)src)[off];
    else         dst[i] = f2bf(((const float*)src)[off]);
}

// ---------------- CSR build ----------------
__global__ void k_zero(int* __restrict__ p, int n) {
    int i = blockIdx.x * 256 + threadIdx.x;
    if (i < n) p[i] = 0;
}

__global__ void k_hist(const int* __restrict__ dst, int* __restrict__ cnt, int E) {
    int e = blockIdx.x * 256 + threadIdx.x;
    if (e < E) atomicAdd(&cnt[dst[e]], 1);
}

__global__ void k_scan_a(const int* __restrict__ cnt, int* __restrict__ ro,
                         int* __restrict__ bsum, int n) {
    __shared__ int sd[256];
    int t = threadIdx.x;
    int base = blockIdx.x * 1024 + t * 4;
    int v0 = (base + 0 < n) ? cnt[base + 0] : 0;
    int v1 = (base + 1 < n) ? cnt[base + 1] : 0;
    int v2 = (base + 2 < n) ? cnt[base + 2] : 0;
    int v3 = (base + 3 < n) ? cnt[base + 3] : 0;
    int s = v0 + v1 + v2 + v3;
    sd[t] = s; __syncthreads();
    for (int off = 1; off < 256; off <<= 1) {
        int x = 0;
        if (t >= off) x = sd[t - off];
        __syncthreads();
        sd[t] += x;
        __syncthreads();
    }
    int run = sd[t] - s;
    run += v0; if (base + 0 < n) ro[base + 1] = run;
    run += v1; if (base + 1 < n) ro[base + 2] = run;
    run += v2; if (base + 2 < n) ro[base + 3] = run;
    run += v3; if (base + 3 < n) ro[base + 4] = run;
    if (t == 255) bsum[blockIdx.x] = sd[255];
}

__global__ void k_scan_b(int* __restrict__ bsum, int nb) {
    if (threadIdx.x == 0 && blockIdx.x == 0) {
        int acc = 0;
        for (int b = 0; b < nb; b++) { int x = bsum[b]; bsum[b] = acc; acc += x; }
    }
}

__global__ void k_scan_c(int* __restrict__ ro, const int* __restrict__ bsum, int n) {
    int i = blockIdx.x * 256 + threadIdx.x;
    if (i == 0) ro[0] = 0;
    if (i < n) ro[i + 1] += bsum[i >> 10];
}

__global__ void k_scatter(const int* __restrict__ src, const int* __restrict__ dst,
                          const int* __restrict__ ro, int* __restrict__ fill,
                          int* __restrict__ ssrc, int E) {
    int e = blockIdx.x * 256 + threadIdx.x;
    if (e < E) {
        int d = dst[e];
        int p = ro[d] + atomicAdd(&fill[d], 1);
        ssrc[p] = src[e];
    }
}

// ---------------- GEMM: h = act @ W^T  (bf16 in, bf16 out, fp32 acc) ----------------
__global__ __launch_bounds__(256) void k_gemm(const ushort_t* __restrict__ act,
                                              const ushort_t* __restrict__ W,
                                              ushort_t* __restrict__ hb, int N) {
    int wid = threadIdx.x >> 6, lane = threadIdx.x & 63;
    int n0 = (blockIdx.x * 4 + wid) * 16;
    int mrow = lane & 15, quad = lane >> 4;
    int n = n0 + mrow;
    short8 a[4];
    if (n < N) {
        const ushort_t* ar = act + (size_t)n * 128 + quad * 8;
        #pragma unroll
        for (int kt = 0; kt < 4; kt++) a[kt] = *(const short8*)(ar + kt * 32);
    } else {
        #pragma unroll
        for (int kt = 0; kt < 4; kt++) { short8 z = {0,0,0,0,0,0,0,0}; a[kt] = z; }
    }
    #pragma unroll
    for (int t = 0; t < 8; t++) {
        const ushort_t* wr = W + (size_t)(t * 16 + mrow) * 128 + quad * 8;
        floatx4 acc = {0.f, 0.f, 0.f, 0.f};
        #pragma unroll
        for (int kt = 0; kt < 4; kt++) {
            short8 b = *(const short8*)(wr + kt * 32);
            acc = __builtin_amdgcn_mfma_f32_16x16x32_bf16(a[kt], b, acc, 0, 0, 0);
        }
        int col = t * 16 + mrow;
        #pragma unroll
        for (int r = 0; r < 4; r++) {
            int rn = n0 + quad * 4 + r;
            if (rn < N) hb[(size_t)rn * 128 + col] = f2bf(acc[r]);
        }
    }
}

// ---------------- node-level attention scores ----------------
__global__ void k_al(const ushort_t* __restrict__ hb, const ushort_t* __restrict__ asrc,
                     const ushort_t* __restrict__ adst, float* __restrict__ als,
                     float* __restrict__ ald, int N) {
    int idx = blockIdx.x * 256 + threadIdx.x;
    if (idx >= N * 4) return;
    int n = idx >> 2, h = idx & 3;
    const ushort_t* hr = hb + (size_t)n * 128 + h * 32;
    const ushort_t* ar = asrc + h * 32;
    const ushort_t* dr = adst + h * 32;
    float ss = 0.f, sd = 0.f;
    #pragma unroll
    for (int c = 0; c < 16; c++) {
        float2 hv = bf2x(*(const uint32*)(hr + c * 2));
        float2 av = bf2x(*(const uint32*)(ar + c * 2));
        float2 dv = bf2x(*(const uint32*)(dr + c * 2));
        ss += hv.x * av.x + hv.y * av.y;
        sd += hv.x * dv.x + hv.y * dv.y;
    }
    als[idx] = ss; ald[idx] = sd;
}

// ---------------- per-dst softmax + weighted aggregation (one wave / node) ----------------
__global__ __launch_bounds__(64) void k_agg(const int* __restrict__ ro, const int* __restrict__ ssrc,
                                            const ushort_t* __restrict__ hb,
                                            const float* __restrict__ als, const float* __restrict__ ald_,
                                            const ushort_t* __restrict__ bias,
                                            void* __restrict__ outp, int N, int apply_elu,
                                            int is_final, const int* __restrict__ flag) {
    int n = blockIdx.x;
    if (n >= N) return;
    int lane = threadIdx.x;
    int r0 = ro[n], r1 = ro[n + 1];
    floatx4 ad = *(const floatx4*)(ald_ + (size_t)n * 4);

    // pass 1: per-head max of leaky-relu scores
    float m0 = -1e30f, m1 = -1e30f, m2 = -1e30f, m3 = -1e30f;
    for (int i = r0 + lane; i < r1; i += 64) {
        int s = ssrc[i];
        floatx4 as = *(const floatx4*)(als + (size_t)s * 4);
        float t0 = as.x + ad.x; t0 = t0 > 0.f ? t0 : NEG_SLOPE * t0; m0 = fmaxf(m0, t0);
        float t1 = as.y + ad.y; t1 = t1 > 0.f ? t1 : NEG_SLOPE * t1; m1 = fmaxf(m1, t1);
        float t2 = as.z + ad.z; t2 = t2 > 0.f ? t2 : NEG_SLOPE * t2; m2 = fmaxf(m2, t2);
        float t3 = as.w + ad.w; t3 = t3 > 0.f ? t3 : NEG_SLOPE * t3; m3 = fmaxf(m3, t3);
    }
    #pragma unroll
    for (int off = 32; off >= 1; off >>= 1) {
        m0 = fmaxf(m0, __shfl_xor(m0, off));
        m1 = fmaxf(m1, __shfl_xor(m1, off));
        m2 = fmaxf(m2, __shfl_xor(m2, off));
        m3 = fmaxf(m3, __shfl_xor(m3, off));
    }

    // pass 2: exp-weights into LDS, channel-parallel weighted sum
    __shared__ __align__(16) float wsm[256];
    __shared__ int ssm[64];
    float a0 = 0.f, a1 = 0.f;
    float d0 = 0.f, d1 = 0.f, d2 = 0.f, d3 = 0.f;
    int hd = lane >> 4;
    int c0 = lane * 2;
    const ushort_t* hcol = hb + c0;
    for (int base = r0; base < r1; base += 64) {
        int i = base + lane;
        if (i < r1) {
            int s = ssrc[i];
            floatx4 as = *(const floatx4*)(als + (size_t)s * 4);
            float t0 = as.x + ad.x; t0 = t0 > 0.f ? t0 : NEG_SLOPE * t0; float w0 = __expf(t0 - m0); d0 += w0;
            float t1 = as.y + ad.y; t1 = t1 > 0.f ? t1 : NEG_SLOPE * t1; float w1 = __expf(t1 - m1); d1 += w1;
            float t2 = as.z + ad.z; t2 = t2 > 0.f ? t2 : NEG_SLOPE * t2; float w2 = __expf(t2 - m2); d2 += w2;
            float t3 = as.w + ad.w; t3 = t3 > 0.f ? t3 : NEG_SLOPE * t3; float w3 = __expf(t3 - m3); d3 += w3;
            ssm[lane] = s;
            floatx4 w4 = {w0, w1, w2, w3};
            *(floatx4*)(wsm + lane * 4) = w4;
        }
        __syncthreads();
        int cend = min(64, r1 - base);
        #pragma unroll 4
        for (int j = 0; j < cend; j++) {
            int s = ssm[j];
            float wj = wsm[j * 4 + hd];
            float2 hv = bf2x(*(const uint32*)(hcol + (size_t)s * 128));
            a0 += wj * hv.x;
            a1 += wj * hv.y;
        }
        __syncthreads();
    }
    #pragma unroll
    for (int off = 32; off >= 1; off >>= 1) {
        d0 += __shfl_xor(d0, off);
        d1 += __shfl_xor(d1, off);
        d2 += __shfl_xor(d2, off);
        d3 += __shfl_xor(d3, off);
    }
    float den = (hd == 0 ? d0 : hd == 1 ? d1 : hd == 2 ? d2 : d3) + 1e-16f;
    float inv = 1.0f / den;
    float2 bv = bf2x(*(const uint32*)(bias + c0));
    float o0 = a0 * inv + bv.x;
    float o1 = a1 * inv + bv.y;
    if (apply_elu) {
        o0 = o0 > 0.f ? o0 : expm1f(o0);
        o1 = o1 > 0.f ? o1 : expm1f(o1);
    }
    if (is_final && !flag[0]) {
        // harness expects f32 output
        float2 o; o.x = o0; o.y = o1;
        *(float2*)((float*)outp + (size_t)n * 128 + c0) = o;
    } else {
        uint32 pack = (uint32)f2bf(o0) | ((uint32)f2bf(o1) << 16);
        *(uint32*)((ushort_t*)outp + (size_t)n * 128 + c0) = pack;
    }
}

extern "C" void kernel_launch(void* const* d_in, const int* in_sizes, int n_in,
                              void* d_out, int out_size, void* d_ws, size_t ws_size,
                              hipStream_t stream) {
    const void* x = d_in[0];
    const int* src = (const int*)d_in[1];
    const int* dst = (const int*)d_in[2];
    const int N = in_sizes[0] / 128;
    const int E = in_sizes[1];

    char* p = (char*)d_ws;
    auto alloc = [&](size_t bytes) { char* r = p; p += (bytes + 255) & ~(size_t)255; return r; };
    int*      flag  = (int*)alloc(256);
    int*      ro    = (int*)alloc((size_t)(N + 1) * 4);
    int*      ssrc  = (int*)alloc((size_t)E * 4);
    ushort_t* hb    = (ushort_t*)alloc((size_t)N * 128 * 2);
    float*    als   = (float*)alloc((size_t)N * 4 * 4);
    float*    ald   = (float*)alloc((size_t)N * 4 * 4);
    ushort_t* xact  = (ushort_t*)alloc((size_t)N * 128 * 2);   // canonical x, then reused as act
    ushort_t* pblk  = (ushort_t*)alloc((size_t)50304 * 2);     // canonical params

    // cnt/fill/bsum alias into hb space (hb written only after CSR build completes)
    int* cnt  = (int*)hb;
    int* fill = (int*)((char*)hb + (size_t)N * 4);
    int* bsum = (int*)((char*)hb + (size_t)2 * N * 4);

    int g256e = (E + 255) / 256;
    int g256n = (N + 255) / 256;
    int nb = (N + 1023) / 1024;

    k_sniff<<<1, 256, 0, stream>>>((const uint32*)x, flag);
    k_canon<<<(N * 128 + 255) / 256, 256, 0, stream>>>(x, xact, N * 128, flag);
    k_canon_params<<<(50304 + 255) / 256, 256, 0, stream>>>(
        d_in[3], d_in[7], d_in[11],     // W0..2
        d_in[4], d_in[8], d_in[12],     // asrc0..2
        d_in[5], d_in[9], d_in[13],     // adst0..2
        d_in[6], d_in[10], d_in[14],    // b0..2
        pblk, flag);

    k_zero<<<g256n, 256, 0, stream>>>(cnt, N);
    k_zero<<<g256n, 256, 0, stream>>>(fill, N);
    k_hist<<<g256e, 256, 0, stream>>>(dst, cnt, E);
    k_scan_a<<<nb, 256, 0, stream>>>(cnt, ro, bsum, N);
    k_scan_b<<<1, 64, 0, stream>>>(bsum, nb);
    k_scan_c<<<g256n, 256, 0, stream>>>(ro, bsum, N);
    k_scatter<<<g256e, 256, 0, stream>>>(src, dst, ro, fill, ssrc, E);

    int gg = (N + 63) / 64;
    const ushort_t* actin = xact;
    for (int l = 0; l < 3; l++) {
        const ushort_t* Wc = pblk + (size_t)l * 16384;
        const ushort_t* As = pblk + 49152 + l * 128;
        const ushort_t* Ad = pblk + 49536 + l * 128;
        const ushort_t* Bc = pblk + 49920 + l * 128;
        void* outp = (l == 2) ? d_out : (void*)xact;   // in-place act reuse (safe: stream-ordered)
        k_gemm<<<gg, 256, 0, stream>>>(actin, Wc, hb, N);
        k_al<<<(N * 4 + 255) / 256, 256, 0, stream>>>(hb, As, Ad, als, ald, N);
        k_agg<<<N, 64, 0, stream>>>(ro, ssrc, hb, als, ald, Bc, outp, N, l < 2 ? 1 : 0,
                                    l == 2 ? 1 : 0, flag);
        actin = xact;
    }
}